// Round 6
// baseline (22337.407 us; speedup 1.0000x reference)
//
#include <hip/hip_runtime.h>

#define SLEN 512
#define BATCH 64
#define IDIM 256
#define HDIM 1024
#define ODIM 128
#define NBLK 256
#define NTHR 512
#define AGENT __HIP_MEMORY_SCOPE_AGENT

typedef unsigned short ushortT;
typedef __attribute__((ext_vector_type(8))) short short8;
typedef __attribute__((ext_vector_type(4))) float f32x4;

__device__ __forceinline__ ushortT f2bf(float f) {
  unsigned u = __float_as_uint(f);
  unsigned r = (u + 0x7FFFu + ((u >> 16) & 1u)) >> 16;
  return (ushortT)r;
}

// pack A/B fragment halves: src[0..3] -> e0..3, src[16..19] -> e4..7
__device__ __forceinline__ void pack2(const float* __restrict__ s, ushortT* d) {
  float4 a = *(const float4*)s;
  float4 b = *(const float4*)(s + 16);
  short8 v;
  v[0]=(short)f2bf(a.x); v[1]=(short)f2bf(a.y); v[2]=(short)f2bf(a.z); v[3]=(short)f2bf(a.w);
  v[4]=(short)f2bf(b.x); v[5]=(short)f2bf(b.y); v[6]=(short)f2bf(b.z); v[7]=(short)f2bf(b.w);
  *(short8*)d = v;
}

// store one f32 into fragment-ordered bf16 mirror at (row, column cL)
__device__ __forceinline__ void mir_store(ushortT* M, int row, int cL, float v) {
  int kt = cL >> 5, c5 = cL & 31;
  int h = c5 >> 4, g = (c5 >> 2) & 3, j = c5 & 3;
  int u = ((kt * 4 + (row >> 4)) * 64) + 16 * g + (row & 15);
  M[(size_t)u * 8 + h * 4 + j] = f2bf(v);
}

// Parallel-sweep grid barrier (proven R5): 64 leaves, block0/wave0 sweep, 64 flags.
__device__ __forceinline__ void gsync(unsigned* sy, int blk, int tid, unsigned idx) {
  __syncthreads();
  if (tid == 0) {
    __threadfence();
    __hip_atomic_fetch_add(&sy[16 * (blk >> 2)], 1u, __ATOMIC_RELAXED, AGENT);
  }
  if (blk == 0 && tid < 64) {
    const unsigned tgt = 4u * idx;
    while (__hip_atomic_load(&sy[16 * tid], __ATOMIC_RELAXED, AGENT) < tgt)
      __builtin_amdgcn_s_sleep(1);
    __threadfence();
    __hip_atomic_store(&sy[1024 + 16 * tid], idx, __ATOMIC_RELAXED, AGENT);
  }
  if (tid == 0) {
    unsigned* f = &sy[1024 + 16 * (blk >> 2)];
    while (__hip_atomic_load(f, __ATOMIC_RELAXED, AGENT) < idx)
      __builtin_amdgcn_s_sleep(1);
    __threadfence();
  }
  __syncthreads();
}

// ---- 64x16 output stage (4 M-tiles x 2 K-halves), NC<=16 weight cols ----
template<int NKT, int SPLIT, int NC>
__device__ __forceinline__ f32x4 stage_mm16(
    const ushortT* __restrict__ mA, const ushortT* __restrict__ mB,
    const ushortT* WL, float (*red)[64][4], int l, int w)
{
  const int mt = w & 3, kh = w >> 2;
  constexpr int H = NKT / 2;
  const int lo = kh * H;
  const int g = l >> 4, col = l & 15;
  f32x4 acc = {0.f, 0.f, 0.f, 0.f};
  short8 af[H];
  #pragma unroll
  for (int t = 0; t < H; ++t) {
    const int kt = lo + t;
    const ushortT* p = (kt < SPLIT)
        ? mA + (size_t)((kt * 4 + mt) * 64 + l) * 8
        : mB + (size_t)(((kt - SPLIT) * 4 + mt) * 64 + l) * 8;
    af[t] = *(const short8*)p;
  }
  #pragma unroll
  for (int t = 0; t < H; ++t) {
    short8 b = {0,0,0,0,0,0,0,0};
    if (col < NC)
      b = *(const short8*)(&WL[(size_t)(((lo + t) * 4 + g) * NC + col) * 8]);
    acc = __builtin_amdgcn_mfma_f32_16x16x32_bf16(af[t], b, acc, 0, 0, 0);
  }
  if (w >= 4) *(f32x4*)&red[w - 4][l][0] = acc;
  __syncthreads();
  if (w < 4) { f32x4 o = *(f32x4*)&red[w][l][0]; acc += o; }
  return acc;
}

// ---- 32x32 output stage (2 M x 2 N x 2 Kh), 32 weight cols in WA ----
template<int NKT, int SPLIT>
__device__ __forceinline__ f32x4 stageA32(
    const ushortT* __restrict__ mA, const ushortT* __restrict__ mB,
    const ushortT* WA, float (*red)[64][4], int l, int w, int mtg)
{
  const int Nt = w & 1, kh = (w >> 1) & 1, Mt2 = w >> 2;
  constexpr int H = NKT / 2;
  const int lo = kh * H;
  const int g = l >> 4, col = l & 15;
  f32x4 acc = {0.f, 0.f, 0.f, 0.f};
  short8 af[H];
  #pragma unroll
  for (int t = 0; t < H; ++t) {
    const int kt = lo + t;
    const ushortT* p = (kt < SPLIT)
        ? mA + (size_t)((kt * 4 + mtg) * 64 + l) * 8
        : mB + (size_t)(((kt - SPLIT) * 4 + mtg) * 64 + l) * 8;
    af[t] = *(const short8*)p;
  }
  #pragma unroll
  for (int t = 0; t < H; ++t) {
    short8 b = *(const short8*)(&WA[(size_t)(((lo + t) * 4 + g) * 32 + Nt * 16 + col) * 8]);
    acc = __builtin_amdgcn_mfma_f32_16x16x32_bf16(af[t], b, acc, 0, 0, 0);
  }
  const int slot = Mt2 * 2 + Nt;
  if (kh) *(f32x4*)&red[slot][l][0] = acc;
  __syncthreads();
  if (!kh) { f32x4 o = *(f32x4*)&red[slot][l][0]; acc += o; }
  return acc;
}

__global__ __launch_bounds__(NTHR) void gru_pipe(
    const float* __restrict__ x,
    const float* __restrict__ Wr0, const float* __restrict__ br0,
    const float* __restrict__ Wz0, const float* __restrict__ bz0,
    const float* __restrict__ Wh0, const float* __restrict__ bh0,
    const float* __restrict__ Wr1, const float* __restrict__ br1,
    const float* __restrict__ Wz1, const float* __restrict__ bz1,
    const float* __restrict__ Wh1, const float* __restrict__ bh1,
    const float* __restrict__ Wout, const float* __restrict__ bout,
    float* __restrict__ out, char* __restrict__ ws)
{
  __shared__ ushortT WSH[73728];     // 144 KB, per-group partitioned
  __shared__ float red[4][64][4];

  const int blk = blockIdx.x;
  const int tid = threadIdx.x;
  const int l = tid & 63;
  const int w = tid >> 6;
  const int g = l >> 4;
  const int colL = l & 15;
  const int Nt = w & 1;
  const int mtg = ((blk & 1) << 1) + (w >> 2);   // M-split mirror tile index

  unsigned* sy = (unsigned*)ws;                      // 8 KB
  float* h0f  = (float*)(ws + 8192);                 // 256 KB (zeroed)
  float* h1f  = (float*)(ws + 270336);               // 2 x 256 KB (zeroed)
  float* z0f  = (float*)(ws + 794624);
  float* z1f  = (float*)(ws + 1056768);
  ushortT* Mh0  = (ushortT*)(ws + 1318912);          // 2 x 128 KB (zeroed)
  ushortT* Mh1  = (ushortT*)(ws + 1581056);          // 2 x 128 KB (zeroed)
  ushortT* Mrh0 = (ushortT*)(ws + 1843200);          // 128 KB
  ushortT* Mrh1 = (ushortT*)(ws + 1974272);          // 128 KB
  ushortT* Mx   = (ushortT*)(ws + 2105344);          // 2 x 32 KB

  // ---- one-time weight staging (bf16, fragment order) ----
  if (blk < 128) {
    const int cg = blk >> 1;
    for (int u = tid; u < 40 * 4 * 32; u += NTHR) {          // r0|z0, 32 cols
      int kt = u >> 7, gg = (u >> 5) & 3, c = u & 31;
      const float* src = (c < 16 ? Wr0 + (size_t)(cg * 16 + c) * 1280
                                 : Wz0 + (size_t)(cg * 16 + c - 16) * 1280)
                         + kt * 32 + gg * 4;
      pack2(src, &WSH[(size_t)u * 8]);
    }
    if (blk < 64) {
      for (int u = tid; u < 40 * 4 * 16; u += NTHR) {        // h0, 16 cols
        int kt = u >> 6, gg = (u >> 4) & 3, c = u & 15;
        pack2(Wh0 + (size_t)(blk * 16 + c) * 1280 + kt * 32 + gg * 4,
              &WSH[40960 + (size_t)u * 8]);
      }
    } else {
      for (int u = tid; u < 64 * 4 * 16; u += NTHR) {        // h1, 16 cols
        int kt = u >> 6, gg = (u >> 4) & 3, c = u & 15;
        pack2(Wh1 + (size_t)((blk - 64) * 16 + c) * 2048 + kt * 32 + gg * 4,
              &WSH[40960 + (size_t)u * 8]);
      }
    }
  } else {
    const int cg = (blk - 128) >> 1;
    for (int u = tid; u < 64 * 4 * 32; u += NTHR) {          // r1|z1, 32 cols
      int kt = u >> 7, gg = (u >> 5) & 3, c = u & 31;
      const float* src = (c < 16 ? Wr1 + (size_t)(cg * 16 + c) * 2048
                                 : Wz1 + (size_t)(cg * 16 + c - 16) * 2048)
                         + kt * 32 + gg * 4;
      pack2(src, &WSH[(size_t)u * 8]);
    }
    if (blk < 144) {
      for (int u = tid; u < 32 * 4 * 8; u += NTHR) {         // out, 8 cols
        int kt = u >> 5, gg = (u >> 3) & 3, c = u & 7;
        pack2(Wout + (size_t)((blk - 128) * 8 + c) * 1024 + kt * 32 + gg * 4,
              &WSH[65536 + (size_t)u * 8]);
      }
    }
  }
  // x(0) mirror -> Mx buf 0 (blocks 144-207, 32 units each)
  if (blk >= 144 && blk < 208 && tid < 32) {
    int u = ((blk - 144) << 5) + tid;        // 0..2047
    int kt = u >> 8, mtu = (u >> 6) & 3, lane = u & 63;
    int row = (mtu << 4) + (lane & 15), gg = lane >> 4;
    pack2(x + (size_t)row * IDIM + (kt << 5) + (gg << 2), Mx + (size_t)u * 8);
  }

  // ---- per-thread constants ----
  float biasA = 0.f, biasB = 0.f, boV = 0.f;
  int colgA = 0, cgB = 0;
  if (blk < 128) {
    colgA = (blk >> 1) * 16 + colL;
    biasA = Nt ? bz0[colgA] : br0[colgA];
  } else {
    colgA = ((blk - 128) >> 1) * 16 + colL;
    biasA = Nt ? bz1[colgA] : br1[colgA];
  }
  if (blk < 64)       { cgB = (blk << 4) + colL;        biasB = bh0[cgB]; }
  else if (blk < 128) { cgB = ((blk - 64) << 4) + colL; biasB = bh1[cgB]; }
  else if (blk < 144) { if (colL < 8) boV = bout[((blk - 128) << 3) + colL]; }

  unsigned sidx = 0;
  gsync(sy, blk, tid, ++sidx);

  for (int i = 0; i <= SLEN; ++i) {
    const int pc = i & 1, pp = (i ^ 1) & 1;
    const ushortT* MxP  = Mx  + (size_t)pc * 16384;
    const ushortT* Mh0p = Mh0 + (size_t)pp * 65536;
    const ushortT* Mh1p = Mh1 + (size_t)pp * 65536;
    const float*   h1prev = h1f + (size_t)pp * 65536;
    float*         h1cur  = h1f + (size_t)pc * 65536;
    ushortT* Mh0w = Mh0 + (size_t)pc * 65536;
    ushortT* Mh1w = Mh1 + (size_t)pc * 65536;

    // ================= Phase A: gates (32 cols x 32 rows per block) ==========
    if (blk < 128) {
      if (i < SLEN) {
        f32x4 acc = stageA32<40, 8>(MxP, Mh0p, WSH, red, l, w, mtg);
        if (!((w >> 1) & 1)) {
          const int rowb = ((blk & 1) << 5) + ((w >> 2) << 4) + (g << 2);
          #pragma unroll
          for (int r = 0; r < 4; ++r) {
            int row = rowb + r;
            float sg = 1.f / (1.f + __expf(-(acc[r] + biasA)));
            if (!Nt) mir_store(Mrh0, row, colgA, sg * h0f[(size_t)row * HDIM + colgA]);
            else     z0f[(size_t)row * HDIM + colgA] = sg;
          }
        }
      }
    } else {
      if (i >= 1) {
        f32x4 acc = stageA32<64, 32>(Mh0p, Mh1p, WSH, red, l, w, mtg);
        if (!((w >> 1) & 1)) {
          const int rowb = ((blk & 1) << 5) + ((w >> 2) << 4) + (g << 2);
          #pragma unroll
          for (int r = 0; r < 4; ++r) {
            int row = rowb + r;
            float sg = 1.f / (1.f + __expf(-(acc[r] + biasA)));
            if (!Nt) mir_store(Mrh1, row, colgA, sg * h1prev[(size_t)row * HDIM + colgA]);
            else     z1f[(size_t)row * HDIM + colgA] = sg;
          }
        }
      }
    }
    gsync(sy, blk, tid, ++sidx);

    // ================= Phase B: candidates + out + x-pack ====================
    if (blk < 64) {
      if (i < SLEN) {
        f32x4 acc = stage_mm16<40, 8, 16>(MxP, Mrh0, WSH + 40960, red, l, w);
        if (w < 4) {
          #pragma unroll
          for (int r = 0; r < 4; ++r) {
            int row = (w << 4) + (g << 2) + r;
            float ht = tanhf(acc[r] + biasB);
            float zv = z0f[(size_t)row * HDIM + cgB];
            float hp = h0f[(size_t)row * HDIM + cgB];
            float hn = fmaf(zv, ht - hp, hp);
            h0f[(size_t)row * HDIM + cgB] = hn;
            mir_store(Mh0w, row, cgB, hn);
          }
        }
      }
    } else if (blk < 128) {
      if (i >= 1) {
        f32x4 acc = stage_mm16<64, 32, 16>(Mh0p, Mrh1, WSH + 40960, red, l, w);
        if (w < 4) {
          #pragma unroll
          for (int r = 0; r < 4; ++r) {
            int row = (w << 4) + (g << 2) + r;
            float ht = tanhf(acc[r] + biasB);
            float zv = z1f[(size_t)row * HDIM + cgB];
            float hp = h1prev[(size_t)row * HDIM + cgB];
            float hn = fmaf(zv, ht - hp, hp);
            h1cur[(size_t)row * HDIM + cgB] = hn;
            mir_store(Mh1w, row, cgB, hn);
          }
        }
      }
    } else if (blk < 144) {
      if (i >= 2) {
        f32x4 acc = stage_mm16<32, 32, 8>(Mh1p, Mh1p, WSH + 65536, red, l, w);
        if (w < 4 && colL < 8) {
          const int jo = ((blk - 128) << 3) + colL;
          #pragma unroll
          for (int r = 0; r < 4; ++r) {
            int row = (w << 4) + (g << 2) + r;
            out[((size_t)(i - 2) * BATCH + row) * ODIM + jo] = acc[r] + boV;
          }
        }
      }
    } else if (blk < 208) {
      if (i + 1 < SLEN && tid < 32) {
        ushortT* MxW = Mx + (size_t)pp * 16384;
        int u = ((blk - 144) << 5) + tid;
        int kt = u >> 8, mtu = (u >> 6) & 3, lane = u & 63;
        int row = (mtu << 4) + (lane & 15), gg = lane >> 4;
        pack2(x + ((size_t)(i + 1) * BATCH + row) * IDIM + (kt << 5) + (gg << 2),
              MxW + (size_t)u * 8);
      }
    }
    gsync(sy, blk, tid, ++sidx);
  }

  // ---- epilogue: out(SLEN-1) from Mh1 parity 0; finals h0f|h1f[0] contiguous ----
  if (blk >= 128 && blk < 144) {
    f32x4 acc = stage_mm16<32, 32, 8>(Mh1, Mh1, WSH + 65536, red, l, w);
    if (w < 4 && colL < 8) {
      const int jo = ((blk - 128) << 3) + colL;
      #pragma unroll
      for (int r = 0; r < 4; ++r) {
        int row = (w << 4) + (g << 2) + r;
        out[((size_t)(SLEN - 1) * BATCH + row) * ODIM + jo] = acc[r] + boV;
      }
    }
  }
  {
    const size_t base = (size_t)SLEN * BATCH * ODIM;
    const int u = blk * NTHR + tid;          // 0..131071
    out[base + u] = h0f[u];                  // h0f then h1f[0], contiguous
  }
}

extern "C" void kernel_launch(void* const* d_in, const int* in_sizes, int n_in,
                              void* d_out, int out_size, void* d_ws, size_t ws_size,
                              hipStream_t stream) {
  const float* xx  = (const float*)d_in[0];
  const float* Wr0 = (const float*)d_in[1];
  const float* br0 = (const float*)d_in[2];
  const float* Wz0 = (const float*)d_in[3];
  const float* bz0 = (const float*)d_in[4];
  const float* Wh0 = (const float*)d_in[5];
  const float* bh0 = (const float*)d_in[6];
  const float* Wr1 = (const float*)d_in[7];
  const float* br1 = (const float*)d_in[8];
  const float* Wz1 = (const float*)d_in[9];
  const float* bz1 = (const float*)d_in[10];
  const float* Wh1 = (const float*)d_in[11];
  const float* bh1 = (const float*)d_in[12];
  const float* Wou = (const float*)d_in[13];
  const float* bou = (const float*)d_in[14];

  // zero state region (sy, h0f, h1f[2], z, mirrors)
  hipMemsetAsync(d_ws, 0, 2170880, stream);

  gru_pipe<<<dim3(NBLK), dim3(NTHR), 0, stream>>>(
      xx, Wr0, br0, Wz0, bz0, Wh0, bh0,
      Wr1, br1, Wz1, bz1, Wh1, bh1, Wou, bou,
      (float*)d_out, (char*)d_ws);
}